// Round 2
// baseline (2710.054 us; speedup 1.0000x reference)
//
#include <hip/hip_runtime.h>

// Problem constants: B=4, N=4096 -> nPoints=16384
#define KN 32     // neighbors per point
#define FF 64     // input feature dim
#define CC 256    // H*D output channels (H=16 heads, D=16)
#define KV_STRIDE 260              // pad 256->260: attention reads/writes are 2-way bank aliased (free)
#define VOFF (KN * KV_STRIDE)      // V offset inside kvS

// ---------------------------------------------------------------------------
// Faithful-reshape semantics (the reference's plain reshape mixes axes!):
//   K[b,n,h,k,d] = K_proj[b,n, j = 2h + (k>>4), ch = (k&15)*16 + d]
//   V likewise; Q[b,n,h,0,d] = Q_proj[b,n, h*16+d].
// Head h uses only neighbors 2h, 2h+1; its 32 keys are the 16 projection-head
// slices of each of those 2 neighbors.
// ---------------------------------------------------------------------------

// Small pre-pass: Qpre[p,c] = (query[p] . Wq[:,c] + bq[c]) * 0.25   (0.25 = 1/sqrt(D))
__global__ __launch_bounds__(256, 2)
void qproj_kernel(const float* __restrict__ query,
                  const float* __restrict__ Wq,
                  const float* __restrict__ bq,
                  float* __restrict__ Qout, int nPoints)
{
    __shared__ float qS[FF];
    const int c = threadIdx.x;
    float wq[FF];
#pragma unroll
    for (int f = 0; f < FF; ++f) wq[f] = Wq[f * CC + c];
    const float bqc = bq[c];
    for (int p = blockIdx.x; p < nPoints; p += gridDim.x) {
        if (c < FF / 4)
            ((float4*)qS)[c] = ((const float4*)(query + (size_t)p * FF))[c];
        __syncthreads();
        float acc = bqc;
#pragma unroll
        for (int f = 0; f < FF; ++f) acc = fmaf(qS[f], wq[f], acc);
        Qout[(size_t)p * CC + c] = acc * 0.25f;
        __syncthreads();   // protect qS before next iteration's restage
    }
}

template <bool PRE_Q>
__global__ __launch_bounds__(256, 2)
void attn_main(const float* __restrict__ inp,
               const float* __restrict__ query,
               const float* __restrict__ Wq,
               const float* __restrict__ bq,
               const float* __restrict__ Wk,
               const float* __restrict__ bk,
               const float* __restrict__ Wv,
               const float* __restrict__ bv,
               const float* __restrict__ Qpre,
               float* __restrict__ out, int nPoints)
{
    __shared__ __align__(16) float inpS[KN * FF];       // 8 KiB, broadcast-read
    __shared__ float kvS[2 * KN * KV_STRIDE];           // 65 KiB: K then V, padded stride
    __shared__ float qS[FF];                            // fallback path only

    const int c = threadIdx.x;
    const int h = c >> 4;
    const int d = c & 15;

    // Wk/Wv column c in registers for the whole kernel
    float wk[FF], wv[FF];
#pragma unroll
    for (int f = 0; f < FF; ++f) {
        wk[f] = Wk[f * CC + c];
        wv[f] = Wv[f * CC + c];
    }
    const float bkc = bk[c];
    const float bvc = bv[c];
    const float bqc = bq[c];

    for (int p = blockIdx.x; p < nPoints; p += gridDim.x) {
        // ---- stage inp row (512 float4) [+ query row on fallback] ----
        const float4* __restrict__ src = (const float4*)(inp + (size_t)p * (KN * FF));
        float4* dst = (float4*)inpS;
        dst[c]       = src[c];
        dst[c + 256] = src[c + 256];
        if (!PRE_Q && c < FF / 4)
            ((float4*)qS)[c] = ((const float4*)(query + (size_t)p * FF))[c];

        float qc;   // pre-scaled Q for this lane's (h,d)
        if (PRE_Q) qc = Qpre[(size_t)p * CC + c];   // issue before barrier, independent of LDS

        __syncthreads();   // A: staging visible; also orders prev-iter kvS reads vs writes below

        if (!PRE_Q) {
            float q0 = bqc;
            const float* WqC = Wq + c;
#pragma unroll
            for (int f = 0; f < FF; ++f) q0 = fmaf(qS[f], WqC[(size_t)f * CC], q0);
            qc = q0 * 0.25f;
        }

        // ---- fused K,V projection for channel c, all 32 neighbors -> LDS ----
#pragma unroll 2
        for (int j = 0; j < KN; ++j) {
            const float4* row = (const float4*)(inpS + j * FF);
            float k0 = 0.f, k1 = 0.f, v0 = 0.f, v1 = 0.f;
#pragma unroll
            for (int t = 0; t < FF / 8; ++t) {
                float4 a = row[2 * t];
                float4 b = row[2 * t + 1];
                k0 = fmaf(a.x, wk[8 * t + 0], k0);
                k0 = fmaf(a.y, wk[8 * t + 1], k0);
                k0 = fmaf(a.z, wk[8 * t + 2], k0);
                k0 = fmaf(a.w, wk[8 * t + 3], k0);
                v0 = fmaf(a.x, wv[8 * t + 0], v0);
                v0 = fmaf(a.y, wv[8 * t + 1], v0);
                v0 = fmaf(a.z, wv[8 * t + 2], v0);
                v0 = fmaf(a.w, wv[8 * t + 3], v0);
                k1 = fmaf(b.x, wk[8 * t + 4], k1);
                k1 = fmaf(b.y, wk[8 * t + 5], k1);
                k1 = fmaf(b.z, wk[8 * t + 6], k1);
                k1 = fmaf(b.w, wk[8 * t + 7], k1);
                v1 = fmaf(b.x, wv[8 * t + 4], v1);
                v1 = fmaf(b.y, wv[8 * t + 5], v1);
                v1 = fmaf(b.z, wv[8 * t + 6], v1);
                v1 = fmaf(b.w, wv[8 * t + 7], v1);
            }
            kvS[j * KV_STRIDE + c]        = k0 + k1 + bkc;
            kvS[VOFF + j * KV_STRIDE + c] = v0 + v1 + bvc;
        }

        __syncthreads();   // B: kvS visible; all inpS reads complete

        // ---- logits: k = kb*16+g -> neighbor j=2h+kb, channel g*16+d ----
        float wgt[KN];
        const int j0 = 2 * h;
#pragma unroll
        for (int k = 0; k < KN; ++k) {
            const int j = j0 + (k >> 4);
            const int g = k & 15;
            float l = qc * kvS[j * KV_STRIDE + g * 16 + d];
            l += __shfl_xor(l, 1);    // butterfly over the 16 lanes of this head
            l += __shfl_xor(l, 2);
            l += __shfl_xor(l, 4);
            l += __shfl_xor(l, 8);
            wgt[k] = l;
        }

        // ---- softmax over 32 (redundant per lane, identical within a head) ----
        float m = wgt[0];
#pragma unroll
        for (int k = 1; k < KN; ++k) m = fmaxf(m, wgt[k]);
        float s = 0.f;
#pragma unroll
        for (int k = 0; k < KN; ++k) {
            float e = __expf(wgt[k] - m);
            wgt[k] = e;
            s += e;
        }
        const float inv = 1.0f / s;

        // ---- output: out[h*16+d] = sum_k w[k] * V[j(k), g(k)*16+d] ----
        float o = 0.f;
#pragma unroll
        for (int k = 0; k < KN; ++k) {
            const int j = j0 + (k >> 4);
            const int g = k & 15;
            o = fmaf(wgt[k], kvS[VOFF + j * KV_STRIDE + g * 16 + d], o);
        }
        out[(size_t)p * CC + c] = o * inv;
        // no trailing barrier needed: next iteration's barrier A orders kvS reuse
    }
}

extern "C" void kernel_launch(void* const* d_in, const int* in_sizes, int n_in,
                              void* d_out, int out_size, void* d_ws, size_t ws_size,
                              hipStream_t stream) {
    const float* inp   = (const float*)d_in[0];
    const float* query = (const float*)d_in[1];
    const float* Wq    = (const float*)d_in[2];
    const float* bq    = (const float*)d_in[3];
    const float* Wk    = (const float*)d_in[4];
    const float* bk    = (const float*)d_in[5];
    const float* Wv    = (const float*)d_in[6];
    const float* bv    = (const float*)d_in[7];
    float* out = (float*)d_out;

    const int nPoints = in_sizes[0] / (KN * FF);   // B*N = 16384
    const size_t qbytes = (size_t)nPoints * CC * sizeof(float);

    if (ws_size >= qbytes) {
        float* Qpre = (float*)d_ws;
        qproj_kernel<<<512, 256, 0, stream>>>(query, Wq, bq, Qpre, nPoints);
        attn_main<true><<<1024, 256, 0, stream>>>(inp, query, Wq, bq, Wk, bk, Wv, bv,
                                                  Qpre, out, nPoints);
    } else {
        attn_main<false><<<1024, 256, 0, stream>>>(inp, query, Wq, bq, Wk, bk, Wv, bv,
                                                   nullptr, out, nPoints);
    }
}

// Round 3
// 344.016 us; speedup vs baseline: 7.8777x; 7.8777x over previous
//
#include <hip/hip_runtime.h>

// Problem constants: B=4, N=4096 -> nPoints=16384
#define KN 32     // neighbors per point
#define FF 64     // input feature dim
#define CC 256    // H*D channels (H=16 heads, D=16)
#define KV_STRIDE 260              // pad 256->260: all access phases <=2-way bank aliased
#define VOFF (KN * KV_STRIDE)      // V offset inside kvS (floats)

// Faithful-reshape semantics (validated R1):
//   K[b,n,h,k,d] = K_proj[b,n, j=2h+(k>>4), ch=(k&15)*16+d];  V likewise.
//   Q[b,n,h,0,d] = Q_proj[b,n, h*16+d].

typedef __attribute__((ext_vector_type(8)))  short bf16x8;   // 8 bf16 = 4 VGPRs
typedef __attribute__((ext_vector_type(16))) float f32x16;   // 32x32 MFMA acc

__device__ inline unsigned short f2bf(float f) {             // fp32->bf16 RNE
    union { float f; unsigned u; } v; v.f = f;
    unsigned u = v.u + 0x7fffu + ((v.u >> 16) & 1u);
    return (unsigned short)(u >> 16);
}
__device__ inline unsigned pack2(float a, float b) {
    return (unsigned)f2bf(a) | ((unsigned)f2bf(b) << 16);
}
__device__ inline bf16x8 pack8(float4 a, float4 b) {
    union { bf16x8 v; unsigned u[4]; } r;
    r.u[0] = pack2(a.x, a.y);  r.u[1] = pack2(a.z, a.w);
    r.u[2] = pack2(b.x, b.y);  r.u[3] = pack2(b.z, b.w);
    return r.v;
}

// Pre-pass (validated R1): Qpre[p,c] = (query[p].Wq[:,c] + bq[c]) * 0.25
__global__ __launch_bounds__(256, 2)
void qproj_kernel(const float* __restrict__ query,
                  const float* __restrict__ Wq,
                  const float* __restrict__ bq,
                  float* __restrict__ Qout, int nPoints)
{
    __shared__ float qS[FF];
    const int c = threadIdx.x;
    float wq[FF];
#pragma unroll
    for (int f = 0; f < FF; ++f) wq[f] = Wq[f * CC + c];
    const float bqc = bq[c];
    for (int p = blockIdx.x; p < nPoints; p += gridDim.x) {
        if (c < FF / 4)
            ((float4*)qS)[c] = ((const float4*)(query + (size_t)p * FF))[c];
        __syncthreads();
        float acc = bqc;
#pragma unroll
        for (int f = 0; f < FF; ++f) acc = fmaf(qS[f], wq[f], acc);
        Qout[(size_t)p * CC + c] = acc * 0.25f;
        __syncthreads();
    }
}

// Main kernel: per-point K/V projection via mfma_f32_32x32x16_bf16, then
// the validated attention wiring reading K/V from LDS.
// Block = 256 threads (4 waves). Wave w owns K-chunks {2w,2w+1} and
// V-chunks {2w,2w+1} (32 channels each). GEMM: M=32 neighbors, N=256, K=64.
template <bool PRE_Q>
__global__ __launch_bounds__(256, 2)
void attn_mfma(const float* __restrict__ inp,
               const float* __restrict__ query,
               const float* __restrict__ Wq,
               const float* __restrict__ bq,
               const float* __restrict__ Wk,
               const float* __restrict__ bk,
               const float* __restrict__ Wv,
               const float* __restrict__ bv,
               const float* __restrict__ Qpre,
               float* __restrict__ out, int nPoints)
{
    __shared__ float kvS[2 * KN * KV_STRIDE];  // K then V, stride-260 padded
    __shared__ float wS[16 * KN];              // per-head softmax weights (intra-wave)
    __shared__ float qS[CC];                   // fallback Q (intra-wave)

    const int tid  = threadIdx.x;
    const int wave = tid >> 6;
    const int L    = tid & 63;
    const int Lm   = L & 31;       // M/N index inside the 32x32 tile
    const int Lh   = L >> 5;       // k-half selector
    const int h    = tid >> 4;     // head 0..15 (attention-phase role)
    const int d    = tid & 15;     // dim within head

    // ---- B fragments (bf16 weights) + bias, built once per block ----
    // B[k][n]: lane holds k = s*16 + Lh*8 + j (j=0..7), n = chunk*32 + Lm
    bf16x8 Bf[4][4];   // [tile: 2xK,2xV][kstep]
    float  bias[4];
#pragma unroll
    for (int t = 0; t < 4; ++t) {
        const float* W  = (t < 2) ? Wk : Wv;
        const float* bb = (t < 2) ? bk : bv;
        const int chunk = 2 * wave + (t & 1);
        const int ch    = chunk * 32 + Lm;
        bias[t] = bb[ch];
#pragma unroll
        for (int s = 0; s < 4; ++s) {
            union { bf16x8 v; unsigned u[4]; } r;
#pragma unroll
            for (int jj = 0; jj < 4; ++jj) {
                const int f = s * 16 + Lh * 8 + 2 * jj;
                r.u[jj] = pack2(W[(size_t)f * CC + ch], W[(size_t)(f + 1) * CC + ch]);
            }
            Bf[t][s] = r.v;
        }
    }

    for (int p = blockIdx.x; p < nPoints; p += gridDim.x) {
        // ---- fallback Q (only lanes of the same wave read qS -> no barrier) ----
        if (!PRE_Q) {
            const float* qr = query + (size_t)p * FF;
            float acc = bq[tid];
            for (int f = 0; f < FF; ++f) acc = fmaf(qr[f], Wq[(size_t)f * CC + tid], acc);
            qS[tid] = acc * 0.25f;
        }

        // ---- A fragments from global (each wave reads the 8KB row once) + MFMA ----
        f32x16 acc[4];
#pragma unroll
        for (int t = 0; t < 4; ++t)
#pragma unroll
            for (int r = 0; r < 16; ++r) acc[t][r] = 0.0f;

        const float* arow = inp + (size_t)p * (KN * FF) + Lm * FF + Lh * 8;
#pragma unroll
        for (int s = 0; s < 4; ++s) {
            float4 a0 = *(const float4*)(arow + s * 16);
            float4 a1 = *(const float4*)(arow + s * 16 + 4);
            bf16x8 Af = pack8(a0, a1);   // A[m=Lm][k = s*16 + Lh*8 + j]
#pragma unroll
            for (int t = 0; t < 4; ++t)
                acc[t] = __builtin_amdgcn_mfma_f32_32x32x16_bf16(Af, Bf[t][s], acc[t], 0, 0, 0);
        }

        // ---- C writeback (+bias) -> kvS.  C: col=Lm-chunk, row=(r&3)+8*(r>>2)+4*Lh ----
#pragma unroll
        for (int t = 0; t < 4; ++t) {
            float* dstbase  = kvS + ((t < 2) ? 0 : VOFF);
            const int col   = (2 * wave + (t & 1)) * 32 + Lm;
            const float bs  = bias[t];
#pragma unroll
            for (int r = 0; r < 16; ++r) {
                const int jrow = (r & 3) + 8 * (r >> 2) + 4 * Lh;
                dstbase[jrow * KV_STRIDE + col] = acc[t][r] + bs;
            }
        }
        __syncthreads();   // kvS ready for attention

        // ---- logits: lane (h,d) owns k = 2d, 2d+1 (same neighbor row) ----
        const float* qrow = PRE_Q ? (Qpre + (size_t)p * CC + h * 16) : (qS + h * 16);
        const int j0  = 2 * h + (d >> 3);          // neighbor for k=2d and 2d+1
        const int g16 = ((2 * d) & 15) * 16;       // channel group base
        const float* Krow = kvS + j0 * KV_STRIDE + g16;
        float l0 = 0.f, l1 = 0.f;
#pragma unroll
        for (int i = 0; i < 16; ++i) {
            const int dp  = (d + i) & 15;          // lane-rotated to break bank conflicts
            const float qv = qrow[dp];
            l0 = fmaf(qv, Krow[dp],      l0);
            l1 = fmaf(qv, Krow[16 + dp], l1);
        }

        // ---- softmax across the head's 16 lanes (masks <16 stay in-head) ----
        float m = fmaxf(l0, l1);
        m = fmaxf(m, __shfl_xor(m, 1));
        m = fmaxf(m, __shfl_xor(m, 2));
        m = fmaxf(m, __shfl_xor(m, 4));
        m = fmaxf(m, __shfl_xor(m, 8));
        float e0 = __expf(l0 - m), e1 = __expf(l1 - m);
        float s2 = e0 + e1;
        s2 += __shfl_xor(s2, 1);
        s2 += __shfl_xor(s2, 2);
        s2 += __shfl_xor(s2, 4);
        s2 += __shfl_xor(s2, 8);
        const float inv = 1.0f / s2;
        wS[h * 32 + 2 * d]     = e0 * inv;   // intra-wave producer/consumer:
        wS[h * 32 + 2 * d + 1] = e1 * inv;   // LDS ops are in-order within a wave
        __builtin_amdgcn_wave_barrier();

        // ---- output: out[h*16+d] = sum_k w[k] * V[j(k), (k&15)*16+d] ----
        float o = 0.f;
        const float* Vbase = kvS + VOFF;
#pragma unroll
        for (int k = 0; k < KN; ++k) {
            const int jk = 2 * h + (k >> 4);
            o = fmaf(wS[h * 32 + k], Vbase[jk * KV_STRIDE + (k & 15) * 16 + d], o);
        }
        out[(size_t)p * CC + tid] = o;

        __syncthreads();   // kvS fully consumed before next point overwrites
    }
}

extern "C" void kernel_launch(void* const* d_in, const int* in_sizes, int n_in,
                              void* d_out, int out_size, void* d_ws, size_t ws_size,
                              hipStream_t stream) {
    const float* inp   = (const float*)d_in[0];
    const float* query = (const float*)d_in[1];
    const float* Wq    = (const float*)d_in[2];
    const float* bq    = (const float*)d_in[3];
    const float* Wk    = (const float*)d_in[4];
    const float* bk    = (const float*)d_in[5];
    const float* Wv    = (const float*)d_in[6];
    const float* bv    = (const float*)d_in[7];
    float* out = (float*)d_out;

    const int nPoints = in_sizes[0] / (KN * FF);   // B*N = 16384
    const size_t qbytes = (size_t)nPoints * CC * sizeof(float);

    if (ws_size >= qbytes) {
        float* Qpre = (float*)d_ws;
        qproj_kernel<<<512, 256, 0, stream>>>(query, Wq, bq, Qpre, nPoints);
        attn_mfma<true><<<1024, 256, 0, stream>>>(inp, query, Wq, bq, Wk, bk, Wv, bv,
                                                  Qpre, out, nPoints);
    } else {
        attn_mfma<false><<<1024, 256, 0, stream>>>(inp, query, Wq, bq, Wk, bk, Wv, bv,
                                                   nullptr, out, nPoints);
    }
}

// Round 4
// 288.320 us; speedup vs baseline: 9.3995x; 1.1932x over previous
//
#include <hip/hip_runtime.h>

// Problem constants: B=4, N=4096 -> nPoints=16384
#define KN 32                 // neighbors per point
#define FF 64                 // input feature dim
#define CC 256                // H*D channels (H=16 heads, D=16)
#define KV_STRIDE 260         // pad 256->260: all kvS phases <=2-way bank aliased (validated R2)
#define VOFF (KN * KV_STRIDE) // V offset inside kvS (floats)
#define NITER 16              // points per block
#define QSTRIDE 264           // ushorts per qAll row (264*2B = 132 dwords, !=0 mod 32)
#define WSTRIDE 33            // wS stride: head h reads bank (h+k)%32 -> conflict-free

// Faithful-reshape semantics (validated R1/R2):
//   K[b,n,h,k,d] = K_proj[b,n, j=2h+(k>>4), ch=(k&15)*16+d];  V likewise.
//   Q[b,n,h,0,d] = Q_proj[b,n, h*16+d].

typedef __attribute__((ext_vector_type(8)))  short bf16x8;   // 8 bf16 = 4 VGPRs
typedef __attribute__((ext_vector_type(16))) float f32x16;   // 32x32 MFMA acc
typedef __attribute__((ext_vector_type(4)))  float f32x4;    // 16x16 MFMA acc

__device__ inline unsigned short f2bf(float f) {             // fp32->bf16 RNE
    union { float f; unsigned u; } v; v.f = f;
    unsigned u = v.u + 0x7fffu + ((v.u >> 16) & 1u);
    return (unsigned short)(u >> 16);
}
__device__ inline unsigned pack2(float a, float b) {
    return (unsigned)f2bf(a) | ((unsigned)f2bf(b) << 16);
}
__device__ inline bf16x8 pack8(float4 a, float4 b) {
    union { bf16x8 v; unsigned u[4]; } r;
    r.u[0] = pack2(a.x, a.y);  r.u[1] = pack2(a.z, a.w);
    r.u[2] = pack2(b.x, b.y);  r.u[3] = pack2(b.z, b.w);
    return r.v;
}

// Single fused kernel. Block = 256 threads (4 waves), NITER points per block.
// Prologue: Q-projection for all 16 points via 16x16x32 MFMA -> qAll (bf16 LDS).
// Main loop: K/V projection via 32x32x16 MFMA (A-row register-prefetched),
// then validated attention wiring from LDS.
__global__ __launch_bounds__(256, 2)
void attn_one(const float* __restrict__ inp,
              const float* __restrict__ query,
              const float* __restrict__ Wq,
              const float* __restrict__ bq,
              const float* __restrict__ Wk,
              const float* __restrict__ bk,
              const float* __restrict__ Wv,
              const float* __restrict__ bv,
              float* __restrict__ out, int nPoints)
{
    __shared__ float kvS[2 * KN * KV_STRIDE];        // 66.5 KB: K then V (fp32)
    __shared__ unsigned short qAllS[NITER * QSTRIDE];// 8.4 KB: pre-scaled Q, bf16
    __shared__ float wS[16 * WSTRIDE];               // softmax weights (intra-wave)

    const int tid  = threadIdx.x;
    const int wave = tid >> 6;
    const int L    = tid & 63;
    const int Lm   = L & 31;       // M/N index inside the 32x32 tile
    const int Lh   = L >> 5;       // k-half selector (32x32x16)
    const int h    = tid >> 4;     // attention head 0..15
    const int d    = tid & 15;     // dim within head
    const int bid  = blockIdx.x;
    const int grid = gridDim.x;

    // ---- stage this block's 16 query rows into kvS scratch (freed later) ----
    float* qIn = kvS;              // 16 rows x 68 floats (pad 64->68)
    {
        const int i  = tid >> 4;           // point slot 0..15
        const int f4 = (tid & 15) * 4;
        const int p  = bid + i * grid;
        if (p < nPoints)
            *(float4*)(qIn + i * 68 + f4) =
                *(const float4*)(query + (size_t)p * FF + f4);
    }

    // ---- prefetch first point's A-row into registers ----
    float4 pf[8];
    {
        const float* arow = inp + (size_t)bid * (KN * FF) + Lm * FF + Lh * 8;
#pragma unroll
        for (int s = 0; s < 4; ++s) {
            pf[2 * s]     = *(const float4*)(arow + s * 16);
            pf[2 * s + 1] = *(const float4*)(arow + s * 16 + 4);
        }
    }

    // ---- Wk/Wv B fragments + bias (validated R2 layout) ----
    // B[k][n]: lane holds k = s*16 + Lh*8 + j, n = chunk*32 + Lm
    bf16x8 Bf[4][4];   // [tile: K0,K1,V0,V1][kstep]
    float  bias[4];
#pragma unroll
    for (int t = 0; t < 4; ++t) {
        const float* W  = (t < 2) ? Wk : Wv;
        const float* bb = (t < 2) ? bk : bv;
        const int ch    = (2 * wave + (t & 1)) * 32 + Lm;
        bias[t] = bb[ch];
#pragma unroll
        for (int s = 0; s < 4; ++s) {
            union { bf16x8 v; unsigned u[4]; } r;
#pragma unroll
            for (int jj = 0; jj < 4; ++jj) {
                const int f = s * 16 + Lh * 8 + 2 * jj;
                r.u[jj] = pack2(W[(size_t)f * CC + ch], W[(size_t)(f + 1) * CC + ch]);
            }
            Bf[t][s] = r.v;
        }
    }

    // ---- Wq B fragments: 4 N-tiles of 16 per wave, K=64 in 2 steps ----
    // 16x16x32 layouts (HW-verified): A[m=lane&15][k=(lane>>4)*8+j],
    // B[k=(lane>>4)*8+j][n=lane&15], C/D col=lane&15 row=(lane>>4)*4+reg.
    const int nq = L & 15;
    const int kq = (L >> 4) * 8;
    bf16x8 Bq[4][2];
    float  bqv[4];
#pragma unroll
    for (int tt = 0; tt < 4; ++tt) {
        const int ch = wave * 64 + tt * 16 + nq;
        bqv[tt] = bq[ch];
#pragma unroll
        for (int s = 0; s < 2; ++s) {
            union { bf16x8 v; unsigned u[4]; } r;
#pragma unroll
            for (int jj = 0; jj < 4; ++jj) {
                const int f = s * 32 + kq + 2 * jj;
                r.u[jj] = pack2(Wq[(size_t)f * CC + ch], Wq[(size_t)(f + 1) * CC + ch]);
            }
            Bq[tt][s] = r.v;
        }
    }

    __syncthreads();   // qIn staged

    // ---- Q-projection MFMA: M=16 points, N=256 channels, K=64 ----
    {
        bf16x8 Aq[2];
        const int im = L & 15;
#pragma unroll
        for (int s = 0; s < 2; ++s) {
            const float* qr = qIn + im * 68 + s * 32 + kq;
            Aq[s] = pack8(*(const float4*)qr, *(const float4*)(qr + 4));
        }
#pragma unroll
        for (int tt = 0; tt < 4; ++tt) {
            f32x4 qa = {0.f, 0.f, 0.f, 0.f};
#pragma unroll
            for (int s = 0; s < 2; ++s)
                qa = __builtin_amdgcn_mfma_f32_16x16x32_bf16(Aq[s], Bq[tt][s], qa, 0, 0, 0);
            const int ch = wave * 64 + tt * 16 + nq;
#pragma unroll
            for (int r = 0; r < 4; ++r) {
                const int ip = (L >> 4) * 4 + r;    // point slot 0..15
                qAllS[ip * QSTRIDE + ch] = f2bf((qa[r] + bqv[tt]) * 0.25f);
            }
        }
    }
    __syncthreads();   // qAll ready; kvS scratch free

    // ================= main loop over this block's points =================
    for (int it = 0, p = bid; p < nPoints; ++it, p += grid) {
        // pack A fragments from prefetched registers
        bf16x8 Af[4];
#pragma unroll
        for (int s = 0; s < 4; ++s) Af[s] = pack8(pf[2 * s], pf[2 * s + 1]);

        // prefetch next point's A-row (latency hidden by MFMA + attention)
        const int pn = p + grid;
        if (pn < nPoints) {
            const float* arow = inp + (size_t)pn * (KN * FF) + Lm * FF + Lh * 8;
#pragma unroll
            for (int s = 0; s < 4; ++s) {
                pf[2 * s]     = *(const float4*)(arow + s * 16);
                pf[2 * s + 1] = *(const float4*)(arow + s * 16 + 4);
            }
        }

        // K/V projection MFMAs
        f32x16 acc[4];
#pragma unroll
        for (int t = 0; t < 4; ++t)
#pragma unroll
            for (int r = 0; r < 16; ++r) acc[t][r] = 0.0f;
#pragma unroll
        for (int s = 0; s < 4; ++s)
#pragma unroll
            for (int t = 0; t < 4; ++t)
                acc[t] = __builtin_amdgcn_mfma_f32_32x32x16_bf16(Af[s], Bf[t][s], acc[t], 0, 0, 0);

        // C writeback (+bias) -> kvS.  C: col=chunk*32+Lm, row=(r&3)+8*(r>>2)+4*Lh
#pragma unroll
        for (int t = 0; t < 4; ++t) {
            float* dstbase = kvS + ((t < 2) ? 0 : VOFF);
            const int col  = (2 * wave + (t & 1)) * 32 + Lm;
            const float bs = bias[t];
#pragma unroll
            for (int r = 0; r < 16; ++r) {
                const int jrow = (r & 3) + 8 * (r >> 2) + 4 * Lh;
                dstbase[jrow * KV_STRIDE + col] = acc[t][r] + bs;
            }
        }
        __syncthreads();   // kvS ready

        // ---- logits: lane (h,d) owns k = 2d, 2d+1 (same neighbor row) ----
        const unsigned short* qrow = qAllS + it * QSTRIDE + h * 16;
        const int j0  = 2 * h + (d >> 3);
        const int g16 = ((2 * d) & 15) * 16;
        const float* Krow = kvS + j0 * KV_STRIDE + g16;
        float l0 = 0.f, l1 = 0.f;
#pragma unroll
        for (int i = 0; i < 16; ++i) {
            const int dp = (d + i) & 15;                 // rotation: banks spread
            const float qv = __uint_as_float((unsigned)qrow[dp] << 16);
            l0 = fmaf(qv, Krow[dp],      l0);
            l1 = fmaf(qv, Krow[16 + dp], l1);
        }

        // ---- softmax across the head's 16 lanes ----
        float m = fmaxf(l0, l1);
        m = fmaxf(m, __shfl_xor(m, 1));
        m = fmaxf(m, __shfl_xor(m, 2));
        m = fmaxf(m, __shfl_xor(m, 4));
        m = fmaxf(m, __shfl_xor(m, 8));
        float e0 = __expf(l0 - m), e1 = __expf(l1 - m);
        float s2 = e0 + e1;
        s2 += __shfl_xor(s2, 1);
        s2 += __shfl_xor(s2, 2);
        s2 += __shfl_xor(s2, 4);
        s2 += __shfl_xor(s2, 8);
        const float inv = 1.0f / s2;
        wS[h * WSTRIDE + 2 * d]     = e0 * inv;   // intra-wave producer/consumer
        wS[h * WSTRIDE + 2 * d + 1] = e1 * inv;
        __builtin_amdgcn_wave_barrier();

        // ---- output: out[h*16+d] = sum_k w[k] * V[j(k), (k&15)*16+d] ----
        float o = 0.f;
        const float* Vbase = kvS + VOFF;
#pragma unroll
        for (int k = 0; k < KN; ++k) {
            const int jk = 2 * h + (k >> 4);
            o = fmaf(wS[h * WSTRIDE + k], Vbase[jk * KV_STRIDE + (k & 15) * 16 + d], o);
        }
        out[(size_t)p * CC + tid] = o;

        __syncthreads();   // kvS fully consumed before next point overwrites
    }
}

extern "C" void kernel_launch(void* const* d_in, const int* in_sizes, int n_in,
                              void* d_out, int out_size, void* d_ws, size_t ws_size,
                              hipStream_t stream) {
    const float* inp   = (const float*)d_in[0];
    const float* query = (const float*)d_in[1];
    const float* Wq    = (const float*)d_in[2];
    const float* bq    = (const float*)d_in[3];
    const float* Wk    = (const float*)d_in[4];
    const float* bk    = (const float*)d_in[5];
    const float* Wv    = (const float*)d_in[6];
    const float* bv    = (const float*)d_in[7];
    float* out = (float*)d_out;

    const int nPoints = in_sizes[0] / (KN * FF);          // B*N = 16384
    const int grid    = (nPoints + NITER - 1) / NITER;    // 1024

    attn_one<<<grid, 256, 0, stream>>>(inp, query, Wq, bq, Wk, bk, Wv, bv,
                                       out, nPoints);
}